// Round 6
// baseline (77.662 us; speedup 1.0000x reference)
//
#include <hip/hip_runtime.h>
#include <hip/hip_bf16.h>

typedef __bf16 bf16x8 __attribute__((ext_vector_type(8)));
typedef float  f32x4  __attribute__((ext_vector_type(4)));

#define MFMA(a, b, c) __builtin_amdgcn_mfma_f32_16x16x32_bf16((a), (b), (c), 0, 0, 0)

// R6: R4's verified skeleton (73.5us @ 3 blocks/CU), register diet -> 4 blocks/CU.
//  - w1 and wp held hi-only (bf16-rounded): -32 VGPR, -20 MFMA/tile. R1/R3/R4
//    showed absmax pinned at 2^-8 across 3-pass/2-pass variants -> these errors
//    sit below the comparison floor. w2 kept split (feeds exp).
//  - __launch_bounds__(256,4): VGPR cap 128 (est. peak ~110), LDS 32KB -> 4
//    blocks/CU = 16 waves/CU. More co-resident blocks = more independent
//    load phases = higher HBM duty cycle (the R4 gap was HBM idle holes).
//  - Everything else byte-identical to R4 (passing, absmax 0.0039).

__device__ __forceinline__ int swz(int row, int byteInRow) {
    return row * 256 + (byteInRow ^ ((row & 7) << 4));
}

__global__ __launch_bounds__(256, 4) void edge_moe_kernel(
    const float* __restrict__ x,  const float* __restrict__ w1,
    const float* __restrict__ b1, const float* __restrict__ w2,
    const float* __restrict__ b2, const float* __restrict__ wp,
    float* __restrict__ outFused, float* __restrict__ outAlpha, int E)
{
    __shared__ __align__(16) char lds[32768];
    char* XH = lds;
    char* HF = lds + 16384;

    const int tid  = threadIdx.x;
    const int lane = tid & 63;
    const int wid  = tid >> 6;   // wave id 0..3 = H-col tile owner (n-split)
    const int lc   = lane & 15;
    const int lg   = lane >> 4;

    // ---- Weight B-fragments ----
    // B-frag (16x16x32): lane holds B[k = kk*32 + lg*8 + j][n], j=0..7.
    bf16x8 w1h[4];               // n = wid*16+lc (this wave's n-tile), hi-only
#pragma unroll
    for (int kk = 0; kk < 4; ++kk) {
        bf16x8 h;
#pragma unroll
        for (int j = 0; j < 8; ++j) {
            int kidx = kk * 32 + lg * 8 + j;
            h[j] = (__bf16)w1[kidx * 64 + wid * 16 + lc];
        }
        w1h[kk] = h;
    }
    bf16x8 w2h[2], w2l[2];       // n = lc (<8), padded 0; split hi/lo
#pragma unroll
    for (int kk = 0; kk < 2; ++kk) {
        bf16x8 h, l;
#pragma unroll
        for (int j = 0; j < 8; ++j) {
            int kidx = kk * 32 + lg * 8 + j;
            float v = (lc < 8) ? w2[kidx * 8 + lc] : 0.0f;
            __bf16 hb = (__bf16)v;
            h[j] = hb; l[j] = (__bf16)(v - (float)hb);
        }
        w2h[kk] = h; w2l[kk] = l;
    }
    bf16x8 wph[4];               // n = lc (<8), padded 0; hi-only
#pragma unroll
    for (int kk = 0; kk < 4; ++kk) {
        bf16x8 h;
#pragma unroll
        for (int j = 0; j < 8; ++j) {
            int kidx = kk * 32 + lg * 8 + j;
            h[j] = (lc < 8) ? (__bf16)wp[kidx * 8 + lc] : (__bf16)0.0f;
        }
        wph[kk] = h;
    }
    const float b1v = b1[wid * 16 + lc];
    const float b2v = (lc < 8) ? b2[lc] : 0.0f;

    const int ntiles = (E + 63) >> 6;
    const int r0 = tid >> 4;          // 0..15 (x-load row)
    const int c8 = tid & 15;          // 8-float column chunk
    const int arow = wid * 16 + lc;   // this wave's phase-F A-frag row

    for (int tile = blockIdx.x; tile < ntiles; tile += gridDim.x) {
        const long long eb = (long long)tile * 64;

        // ---- Load x tile [64][128] f32, coalesced ----
        float4 vr[4][2];
#pragma unroll
        for (int it = 0; it < 4; ++it) {
            long long e = eb + r0 + it * 16;
            if (e > (long long)E - 1) e = E - 1;
            const float4* p = (const float4*)(x + (size_t)e * 128 + c8 * 8);
            vr[it][0] = p[0];
            vr[it][1] = p[1];
        }
        __syncthreads();   // barrier 1: XH(t-1)/HF(t-1) readers done

        // ---- A: convert to bf16 (hi only), write LDS (swizzled) ----
#pragma unroll
        for (int it = 0; it < 4; ++it) {
            int row = r0 + it * 16;
            bf16x8 h;
            const float* f = (const float*)&vr[it][0];
#pragma unroll
            for (int j = 0; j < 8; ++j) h[j] = (__bf16)f[j];
            *(bf16x8*)(XH + swz(row, c8 * 16)) = h;
        }
        __syncthreads();   // barrier 2: x(t) ready

        // ---- D: H = relu(x@w1+b1) for n-tile wid, all 4 m-tiles ----
        // Peel mtt=0 (mt = wid) and stash its A-frags for phase F's x@wp.
        bf16x8 axh[4];
        f32x4 acc[4] = {{0.f,0.f,0.f,0.f},{0.f,0.f,0.f,0.f},{0.f,0.f,0.f,0.f},{0.f,0.f,0.f,0.f}};
#pragma unroll
        for (int kk = 0; kk < 4; ++kk) {
            axh[kk] = *(const bf16x8*)(XH + swz(arow, kk * 64 + lg * 16));
            acc[0] = MFMA(axh[kk], w1h[kk], acc[0]);
        }
#pragma unroll
        for (int mtt = 1; mtt < 4; ++mtt) {
            const int mt = (wid + mtt) & 3;
            const int row = mt * 16 + lc;
#pragma unroll
            for (int kk = 0; kk < 4; ++kk) {
                bf16x8 ah = *(const bf16x8*)(XH + swz(row, kk * 64 + lg * 16));
                acc[mtt] = MFMA(ah, w1h[kk], acc[mtt]);
            }
        }
        // bias + relu -> HF f32 (C-layout: row = mt*16+lg*4+r, col = wid*16+lc)
#pragma unroll
        for (int mtt = 0; mtt < 4; ++mtt) {
            const int mt = (wid + mtt) & 3;
#pragma unroll
            for (int r = 0; r < 4; ++r) {
                float hv = fmaxf(acc[mtt][r] + b1v, 0.f);
                *(float*)(HF + swz(mt * 16 + lg * 4 + r, (wid * 16 + lc) * 4)) = hv;
            }
        }
        __syncthreads();   // barrier 3: H ready (cross-wave)

        // ---- F: logits = H@w2 + b2 (H->bf16 once, w2 split); scores from axh ----
        f32x4 lac = {0.f, 0.f, 0.f, 0.f};
        f32x4 sac = {0.f, 0.f, 0.f, 0.f};
#pragma unroll
        for (int kk = 0; kk < 2; ++kk) {
            int base = kk * 128 + lg * 32;     // f32 bytes: k = kk*32 + lg*8
            f32x4 h0 = *(const f32x4*)(HF + swz(arow, base));
            f32x4 h1 = *(const f32x4*)(HF + swz(arow, base + 16));
            bf16x8 hh;
#pragma unroll
            for (int j = 0; j < 4; ++j) {
                hh[j]     = (__bf16)h0[j];
                hh[j + 4] = (__bf16)h1[j];
            }
            lac = MFMA(hh, w2h[kk], lac);
            lac = MFMA(hh, w2l[kk], lac);
        }
#pragma unroll
        for (int kk = 0; kk < 4; ++kk) {
            sac = MFMA(axh[kk], wph[kk], sac);
        }

        // ---- Softmax over 8 cols (lanes lc<8; no max-sub) + fused dot ----
#pragma unroll
        for (int r = 0; r < 4; ++r) {
            float lv = lac[r] + b2v;           // TEMPERATURE = 1.0
            float p = __expf(lv);
            float s  = p;
            float fs = p * sac[r];
            s  += __shfl_xor(s, 1);  fs += __shfl_xor(fs, 1);
            s  += __shfl_xor(s, 2);  fs += __shfl_xor(fs, 2);
            s  += __shfl_xor(s, 4);  fs += __shfl_xor(fs, 4);
            float inv = 1.0f / s;
            float alpha = p * inv;
            float fv = fs * inv;
            long long edge = eb + wid * 16 + lg * 4 + r;
            if (edge < E) {
                if (lc < 8) outAlpha[edge * 8 + lc] = alpha;
                if (lc == 0) outFused[edge] = fv;
            }
        }
        // loop-top barrier orders next tile's XH/HF overwrite
    }
}

extern "C" void kernel_launch(void* const* d_in, const int* in_sizes, int n_in,
                              void* d_out, int out_size, void* d_ws, size_t ws_size,
                              hipStream_t stream) {
    const float* x  = (const float*)d_in[0];
    const float* w1 = (const float*)d_in[1];
    const float* b1 = (const float*)d_in[2];
    const float* w2 = (const float*)d_in[3];
    const float* b2 = (const float*)d_in[4];
    const float* wp = (const float*)d_in[5];

    const int E = in_sizes[0] / 128;
    float* outF = (float*)d_out;
    float* outA = outF + E;

    const int ntiles = (E + 63) >> 6;
    const int blocks = ntiles < 1024 ? ntiles : 1024;   // 4 blocks/CU x 256 CU
    edge_moe_kernel<<<blocks, 256, 0, stream>>>(x, w1, b1, w2, b2, wp, outF, outA, E);
}

// Round 7
// 76.791 us; speedup vs baseline: 1.0114x; 1.0114x over previous
//
#include <hip/hip_runtime.h>
#include <hip/hip_bf16.h>

typedef __bf16 bf16x8 __attribute__((ext_vector_type(8)));
typedef float  f32x4  __attribute__((ext_vector_type(4)));

#define MFMA(a, b, c) __builtin_amdgcn_mfma_f32_16x16x32_bf16((a), (b), (c), 0, 0, 0)

// R7: R4/R6 hybrid, 2 barriers/tile, late-issue prefetch, 3 blocks/CU.
//  - Weights: w1/wp hi-only, w2 split (R6 diet; absmax pinned at 2^-8 across all
//    precision variants -> free). 48 weight VGPRs.
//  - launch_bounds(256,3) restored: R6's (256,4) spilled (77.7us vs R4 73.5).
//  - Prefetch x(t+1) issued right after barrier B (HF ready): vr live only across
//    phase F + softmax (low-pressure region, ~121 peak), lands before the loop-top
//    conversion. In-flight ~1700cyc > ~900cyc HBM latency.
//  - 2 barriers/tile: the old loop-top barrier was redundant — conversion's only
//    hazard (phase-D XH readers) is already ordered by barrier B(t-1), since no
//    wave can be in D(t-1) once any wave passed B(t-1).
//      convert vr->XH ; barrier A ; phase D (XH->HF) ; barrier B ;
//      issue loads(t+1) ; phase F (HF reads) ; softmax/stores ; loop
// LDS 32KB (XH 16K + HF 16K); XOR swizzle byte^=(row&7)<<4 throughout.

__device__ __forceinline__ int swz(int row, int byteInRow) {
    return row * 256 + (byteInRow ^ ((row & 7) << 4));
}

__global__ __launch_bounds__(256, 3) void edge_moe_kernel(
    const float* __restrict__ x,  const float* __restrict__ w1,
    const float* __restrict__ b1, const float* __restrict__ w2,
    const float* __restrict__ b2, const float* __restrict__ wp,
    float* __restrict__ outFused, float* __restrict__ outAlpha, int E)
{
    __shared__ __align__(16) char lds[32768];
    char* XH = lds;
    char* HF = lds + 16384;

    const int tid  = threadIdx.x;
    const int lane = tid & 63;
    const int wid  = tid >> 6;   // wave id 0..3 = H-col tile owner (n-split)
    const int lc   = lane & 15;
    const int lg   = lane >> 4;

    // ---- Weight B-fragments (built once) ----
    // B-frag (16x16x32): lane holds B[k = kk*32 + lg*8 + j][n], j=0..7.
    bf16x8 w1h[4];               // n = wid*16+lc, hi-only
#pragma unroll
    for (int kk = 0; kk < 4; ++kk) {
        bf16x8 h;
#pragma unroll
        for (int j = 0; j < 8; ++j) {
            int kidx = kk * 32 + lg * 8 + j;
            h[j] = (__bf16)w1[kidx * 64 + wid * 16 + lc];
        }
        w1h[kk] = h;
    }
    bf16x8 w2h[2], w2l[2];       // n = lc (<8), padded 0; split hi/lo (feeds exp)
#pragma unroll
    for (int kk = 0; kk < 2; ++kk) {
        bf16x8 h, l;
#pragma unroll
        for (int j = 0; j < 8; ++j) {
            int kidx = kk * 32 + lg * 8 + j;
            float v = (lc < 8) ? w2[kidx * 8 + lc] : 0.0f;
            __bf16 hb = (__bf16)v;
            h[j] = hb; l[j] = (__bf16)(v - (float)hb);
        }
        w2h[kk] = h; w2l[kk] = l;
    }
    bf16x8 wph[4];               // n = lc (<8), padded 0; hi-only
#pragma unroll
    for (int kk = 0; kk < 4; ++kk) {
        bf16x8 h;
#pragma unroll
        for (int j = 0; j < 8; ++j) {
            int kidx = kk * 32 + lg * 8 + j;
            h[j] = (lc < 8) ? (__bf16)wp[kidx * 8 + lc] : (__bf16)0.0f;
        }
        wph[kk] = h;
    }
    const float b1v = b1[wid * 16 + lc];
    const float b2v = (lc < 8) ? b2[lc] : 0.0f;

    const int ntiles = (E + 63) >> 6;
    const int r0 = tid >> 4;          // 0..15 (x-load row)
    const int c8 = tid & 15;          // 8-float column chunk
    const int arow = wid * 16 + lc;   // this wave's phase-F A-frag row

    float4 vr[4][2];   // in-flight x tile; live only from issue (post-B) to convert

#define LOADX(TT) do {                                                        \
        const long long _eb = (long long)(TT) * 64;                           \
        _Pragma("unroll")                                                     \
        for (int it = 0; it < 4; ++it) {                                      \
            long long e = _eb + r0 + it * 16;                                 \
            if (e > (long long)E - 1) e = E - 1;                              \
            const float4* p = (const float4*)(x + (size_t)e * 128 + c8 * 8);  \
            vr[it][0] = p[0];                                                 \
            vr[it][1] = p[1];                                                 \
        }                                                                     \
    } while (0)

    // Prologue: first tile's loads in flight.
    if (blockIdx.x < ntiles) LOADX(blockIdx.x);

    for (int tile = blockIdx.x; tile < ntiles; tile += gridDim.x) {
        const long long eb = (long long)tile * 64;

        // ---- Convert vr -> XH(t) bf16 (swizzled). No barrier needed before:
        //      all XH(t-1) readers finished before barrier B(t-1). ----
#pragma unroll
        for (int it = 0; it < 4; ++it) {
            int row = r0 + it * 16;
            bf16x8 h;
            const float* f = (const float*)&vr[it][0];
#pragma unroll
            for (int j = 0; j < 8; ++j) h[j] = (__bf16)f[j];
            *(bf16x8*)(XH + swz(row, c8 * 16)) = h;
        }
        __syncthreads();   // barrier A: XH(t) ready AND HF(t-1) readers done

        // ---- D: H = relu(x@w1+b1) for n-tile wid, all 4 m-tiles ----
        bf16x8 axh[4];
        f32x4 acc[4] = {{0.f,0.f,0.f,0.f},{0.f,0.f,0.f,0.f},{0.f,0.f,0.f,0.f},{0.f,0.f,0.f,0.f}};
#pragma unroll
        for (int kk = 0; kk < 4; ++kk) {
            axh[kk] = *(const bf16x8*)(XH + swz(arow, kk * 64 + lg * 16));
            acc[0] = MFMA(axh[kk], w1h[kk], acc[0]);
        }
#pragma unroll
        for (int mtt = 1; mtt < 4; ++mtt) {
            const int mt = (wid + mtt) & 3;
            const int row = mt * 16 + lc;
#pragma unroll
            for (int kk = 0; kk < 4; ++kk) {
                bf16x8 ah = *(const bf16x8*)(XH + swz(row, kk * 64 + lg * 16));
                acc[mtt] = MFMA(ah, w1h[kk], acc[mtt]);
            }
        }
        // bias + relu -> HF f32 (C-layout: row = mt*16+lg*4+r, col = wid*16+lc)
#pragma unroll
        for (int mtt = 0; mtt < 4; ++mtt) {
            const int mt = (wid + mtt) & 3;
#pragma unroll
            for (int r = 0; r < 4; ++r) {
                float hv = fmaxf(acc[mtt][r] + b1v, 0.f);
                *(float*)(HF + swz(mt * 16 + lg * 4 + r, (wid * 16 + lc) * 4)) = hv;
            }
        }
        __syncthreads();   // barrier B: HF(t) ready; XH(t) readers done

        // ---- Prefetch x(t+1): flies across phase F + softmax + stores ----
        {
            int nxt = tile + (int)gridDim.x;
            if (nxt < ntiles) LOADX(nxt);
        }

        // ---- F: logits = H@w2 + b2 (H->bf16 once, w2 split); scores from axh ----
        f32x4 lac = {0.f, 0.f, 0.f, 0.f};
        f32x4 sac = {0.f, 0.f, 0.f, 0.f};
#pragma unroll
        for (int kk = 0; kk < 2; ++kk) {
            int base = kk * 128 + lg * 32;     // f32 bytes: k = kk*32 + lg*8
            f32x4 h0 = *(const f32x4*)(HF + swz(arow, base));
            f32x4 h1 = *(const f32x4*)(HF + swz(arow, base + 16));
            bf16x8 hh;
#pragma unroll
            for (int j = 0; j < 4; ++j) {
                hh[j]     = (__bf16)h0[j];
                hh[j + 4] = (__bf16)h1[j];
            }
            lac = MFMA(hh, w2h[kk], lac);
            lac = MFMA(hh, w2l[kk], lac);
        }
#pragma unroll
        for (int kk = 0; kk < 4; ++kk) {
            sac = MFMA(axh[kk], wph[kk], sac);
        }

        // ---- Softmax over 8 cols (lanes lc<8; no max-sub) + fused dot ----
#pragma unroll
        for (int r = 0; r < 4; ++r) {
            float lv = lac[r] + b2v;           // TEMPERATURE = 1.0
            float p = __expf(lv);
            float s  = p;
            float fs = p * sac[r];
            s  += __shfl_xor(s, 1);  fs += __shfl_xor(fs, 1);
            s  += __shfl_xor(s, 2);  fs += __shfl_xor(fs, 2);
            s  += __shfl_xor(s, 4);  fs += __shfl_xor(fs, 4);
            float inv = 1.0f / s;
            float alpha = p * inv;
            float fv = fs * inv;
            long long edge = eb + wid * 16 + lg * 4 + r;
            if (edge < E) {
                if (lc < 8) outAlpha[edge * 8 + lc] = alpha;
                if (lc == 0) outFused[edge] = fv;
            }
        }
        // next iteration's conversion is safe without a barrier (see header note)
    }
#undef LOADX
}

extern "C" void kernel_launch(void* const* d_in, const int* in_sizes, int n_in,
                              void* d_out, int out_size, void* d_ws, size_t ws_size,
                              hipStream_t stream) {
    const float* x  = (const float*)d_in[0];
    const float* w1 = (const float*)d_in[1];
    const float* b1 = (const float*)d_in[2];
    const float* w2 = (const float*)d_in[3];
    const float* b2 = (const float*)d_in[4];
    const float* wp = (const float*)d_in[5];

    const int E = in_sizes[0] / 128;
    float* outF = (float*)d_out;
    float* outA = outF + E;

    const int ntiles = (E + 63) >> 6;
    const int blocks = ntiles < 768 ? ntiles : 768;   // 3 blocks/CU x 256 CU
    edge_moe_kernel<<<blocks, 256, 0, stream>>>(x, w1, b1, w2, b2, wp, outF, outA, E);
}